// Round 1
// baseline (318.839 us; speedup 1.0000x reference)
//
#include <hip/hip_runtime.h>
#include <hip/hip_bf16.h>

// B=2, T=2048, C=1024, H=16, Dh=64
// ws layout (bytes):
//   xb   [4096x1024]  bf16 @ 0          (8,388,608)
//   wat  [3072x1024]  bf16 @ 8388608    (6,291,456)   = w_attn^T
//   wpt  [1024x1024]  bf16 @ 14680064   (2,097,152)   = w_proj^T
//   qkv  [4096x3072]  bf16 @ 16777216   (25,165,824)
//   yb   [4096x1024]  bf16 @ 41943040   (8,388,608)
// total 50,331,648 B

typedef __attribute__((ext_vector_type(8))) __bf16 bf16x8;
typedef __attribute__((ext_vector_type(4))) float  floatx4;
typedef __attribute__((ext_vector_type(4))) float  fvec4;
typedef __attribute__((ext_vector_type(4))) short  short4v;

#define MFMA16(a, b, c) __builtin_amdgcn_mfma_f32_16x16x32_bf16(a, b, c, 0, 0, 0)

__device__ inline void store_out(float* p, float v) { *p = v; }
__device__ inline void store_out(__hip_bfloat16* p, float v) { *p = __float2bfloat16(v); }

// ---------------- cast fp32 -> bf16 (elementwise) ----------------
__global__ __launch_bounds__(256) void cast_bf16_kernel(const float* __restrict__ in,
                                                        __hip_bfloat16* __restrict__ out,
                                                        int n) {
  int i = (blockIdx.x * 256 + threadIdx.x) * 4;
  if (i >= n) return;
  fvec4 v = *(const fvec4*)(in + i);
  union { short4v s; __hip_bfloat16 h[4]; } u;
#pragma unroll
  for (int j = 0; j < 4; ++j) u.h[j] = __float2bfloat16(v[j]);
  *(short4v*)((short*)out + i) = u.s;
}

// ------------- transpose + cast: in[rows][cols] f32 -> out[cols][rows] bf16 -------------
__global__ __launch_bounds__(256) void transpose_cast_kernel(const float* __restrict__ in,
                                                             __hip_bfloat16* __restrict__ out,
                                                             int rows, int cols) {
  __shared__ float tile[32][33];
  const int tx = threadIdx.x, ty = threadIdx.y;
  const int c0 = blockIdx.x * 32, r0 = blockIdx.y * 32;
#pragma unroll
  for (int i = 0; i < 32; i += 8)
    tile[ty + i][tx] = in[(long)(r0 + ty + i) * cols + c0 + tx];
  __syncthreads();
#pragma unroll
  for (int i = 0; i < 32; i += 8)
    out[(long)(c0 + ty + i) * rows + r0 + tx] = __float2bfloat16(tile[tx][ty + i]);
}

// ------------- GEMM: C[M,N] = A[M,K] * Bt[N,K]^T  (bf16 in, OutT out) -------------
// 128x128 block tile, BK=32, 256 threads (4 waves), wave -> 64x64 (4x4 MFMA tiles)
template <typename OutT>
__global__ __launch_bounds__(256) void gemm_bt_kernel(const __hip_bfloat16* __restrict__ A,
                                                      const __hip_bfloat16* __restrict__ Bt,
                                                      OutT* __restrict__ C,
                                                      int M, int N, int K) {
  // pad rows to 40 elems (80 B): 16-lane b128 reads land on (5m+c) mod 8 -> 2-way max (free)
  __shared__ __align__(16) __hip_bfloat16 As[128 * 40];
  __shared__ __align__(16) __hip_bfloat16 Bs[128 * 40];
  const int tid = threadIdx.x;
  const int lane = tid & 63, wv = tid >> 6;
  const int l15 = lane & 15, quad = lane >> 4;
  const int wm = wv >> 1, wn = wv & 1;
  const long m0 = (long)blockIdx.y * 128, n0 = (long)blockIdx.x * 128;
  floatx4 acc[4][4] = {};
  const int nk = K >> 5;
  for (int kt = 0; kt < nk; ++kt) {
    const int k0 = kt << 5;
    __syncthreads();
#pragma unroll
    for (int it = 0; it < 2; ++it) {
      const int c = it * 256 + tid;
      const int row = c >> 2, col = (c & 3) << 3;
      *(bf16x8*)(As + row * 40 + col) = *(const bf16x8*)(A + (m0 + row) * K + k0 + col);
      *(bf16x8*)(Bs + row * 40 + col) = *(const bf16x8*)(Bt + (n0 + row) * K + k0 + col);
    }
    __syncthreads();
    bf16x8 af[4], bfr[4];
#pragma unroll
    for (int t = 0; t < 4; ++t) {
      af[t]  = *(const bf16x8*)(As + (wm * 64 + t * 16 + l15) * 40 + quad * 8);
      bfr[t] = *(const bf16x8*)(Bs + (wn * 64 + t * 16 + l15) * 40 + quad * 8);
    }
#pragma unroll
    for (int mt = 0; mt < 4; ++mt)
#pragma unroll
      for (int nt = 0; nt < 4; ++nt)
        acc[mt][nt] = MFMA16(af[mt], bfr[nt], acc[mt][nt]);
  }
  // epilogue: D row = quad*4+r, col = l15 (verified m89/m91 C/D layout)
#pragma unroll
  for (int mt = 0; mt < 4; ++mt)
#pragma unroll
    for (int nt = 0; nt < 4; ++nt)
#pragma unroll
      for (int r = 0; r < 4; ++r) {
        const long row = m0 + wm * 64 + mt * 16 + quad * 4 + r;
        const long col = n0 + wn * 64 + nt * 16 + l15;
        store_out(C + row * N + col, acc[mt][nt][r]);
      }
}

// ------------- flash-style causal attention -------------
// qkv: [B*T, 3072] bf16 (q: +0, k: +1024, v: +2048; head h at h*64)
// y:   [B*T, 1024] bf16
// block = (q_tile qt, head h, batch b); 256 threads, 4 waves x 16 q-rows; D=64; k-tile=64
__global__ __launch_bounds__(256) void attn_kernel(const __hip_bfloat16* __restrict__ qkv,
                                                   __hip_bfloat16* __restrict__ y) {
  __shared__ __align__(16) __hip_bfloat16 Ks[64 * 72];       // K-tile, row-major [k][d]
  __shared__ __align__(16) __hip_bfloat16 Vt[64 * 72];       // V-tile transposed [d][k]
  __shared__ __align__(16) __hip_bfloat16 Ps[4 * 16 * 72];   // per-wave P [16][64]
  const int tid = threadIdx.x;
  const int lane = tid & 63, wv = tid >> 6;
  const int l15 = lane & 15, quad = lane >> 4;
  const int qt = blockIdx.x, h = blockIdx.y, b = blockIdx.z;
  const int q0 = qt * 64;
  const long RS = 3072;

  // Q A-fragments (A[m=l15][k=quad*8+j]), loaded once from global
  bf16x8 aq0, aq1;
  {
    const long tq = (long)b * 2048 + q0 + wv * 16 + l15;
    const __hip_bfloat16* qp = qkv + tq * RS + h * 64 + quad * 8;
    aq0 = *(const bf16x8*)qp;
    aq1 = *(const bf16x8*)(qp + 32);
  }
  float m_i[4], l_i[4];
  floatx4 o[4] = {};
#pragma unroll
  for (int r = 0; r < 4; ++r) { m_i[r] = -1e30f; l_i[r] = 0.f; }

  for (int kt = 0; kt <= qt; ++kt) {
    const int kb = kt * 64;
    __syncthreads();  // protect Ks/Vt against previous iteration's readers
#pragma unroll
    for (int it = 0; it < 2; ++it) {
      const int c = it * 256 + tid;
      const int row = c >> 3, col = (c & 7) << 3;
      const __hip_bfloat16* base = qkv + ((long)b * 2048 + kb + row) * RS + h * 64 + col;
      *(bf16x8*)(Ks + row * 72 + col) = *(const bf16x8*)(base + 1024);
      bf16x8 vvv = *(const bf16x8*)(base + 2048);
      const __hip_bfloat16* vh = (const __hip_bfloat16*)&vvv;
#pragma unroll
      for (int j = 0; j < 8; ++j) Vt[(col + j) * 72 + row] = vh[j];
    }
    __syncthreads();

    // S = Q K^T : B-frag B[d][n]=K[n][d] read from Ks rows
    floatx4 s[4] = {};
#pragma unroll
    for (int nt = 0; nt < 4; ++nt) {
      const __hip_bfloat16* kp = Ks + (nt * 16 + l15) * 72 + quad * 8;
      s[nt] = MFMA16(aq0, *(const bf16x8*)kp, s[nt]);
      s[nt] = MFMA16(aq1, *(const bf16x8*)(kp + 32), s[nt]);
    }

    // scale + causal mask (C layout: row=quad*4+r, col=nt*16+l15)
    float sv[4][4];
#pragma unroll
    for (int nt = 0; nt < 4; ++nt)
#pragma unroll
      for (int r = 0; r < 4; ++r) {
        const int kg = kb + nt * 16 + l15;
        const int qg = q0 + wv * 16 + quad * 4 + r;
        sv[nt][r] = (kg > qg) ? -1e30f : s[nt][r] * 0.125f;
      }

    // online softmax per q-row (rows of a quad; reduce across the quad's 16 lanes)
#pragma unroll
    for (int r = 0; r < 4; ++r) {
      float mx = fmaxf(fmaxf(sv[0][r], sv[1][r]), fmaxf(sv[2][r], sv[3][r]));
#pragma unroll
      for (int off = 1; off < 16; off <<= 1) mx = fmaxf(mx, __shfl_xor(mx, off, 64));
      const float mn = fmaxf(m_i[r], mx);
      const float al = __expf(m_i[r] - mn);
      float rs = 0.f;
#pragma unroll
      for (int nt = 0; nt < 4; ++nt) {
        const float p = __expf(sv[nt][r] - mn);
        sv[nt][r] = p;
        rs += p;
      }
#pragma unroll
      for (int off = 1; off < 16; off <<= 1) rs += __shfl_xor(rs, off, 64);
      m_i[r] = mn;
      l_i[r] = l_i[r] * al + rs;
#pragma unroll
      for (int nt = 0; nt < 4; ++nt) o[nt][r] *= al;
      // C-layout -> LDS (A-layout round trip, per m120 pattern)
#pragma unroll
      for (int nt = 0; nt < 4; ++nt)
        Ps[wv * 1152 + (quad * 4 + r) * 72 + nt * 16 + l15] = __float2bfloat16(sv[nt][r]);
    }
    __syncthreads();

    // O += P V : A-frag from Ps, B-frag B[k][n]=V[k][n]=Vt[n][k]
    const __hip_bfloat16* pp = Ps + wv * 1152 + l15 * 72 + quad * 8;
    const bf16x8 pa0 = *(const bf16x8*)pp;
    const bf16x8 pa1 = *(const bf16x8*)(pp + 32);
#pragma unroll
    for (int nt = 0; nt < 4; ++nt) {
      const __hip_bfloat16* vp = Vt + (nt * 16 + l15) * 72 + quad * 8;
      o[nt] = MFMA16(pa0, *(const bf16x8*)vp, o[nt]);
      o[nt] = MFMA16(pa1, *(const bf16x8*)(vp + 32), o[nt]);
    }
  }

  // epilogue: y[b,t,h*64+d] = O / l
#pragma unroll
  for (int r = 0; r < 4; ++r) {
    const long t = (long)b * 2048 + q0 + wv * 16 + quad * 4 + r;
    const float inv = 1.0f / l_i[r];
#pragma unroll
    for (int nt = 0; nt < 4; ++nt)
      y[t * 1024 + h * 64 + nt * 16 + l15] = __float2bfloat16(o[nt][r] * inv);
  }
}

extern "C" void kernel_launch(void* const* d_in, const int* in_sizes, int n_in,
                              void* d_out, int out_size, void* d_ws, size_t ws_size,
                              hipStream_t stream) {
  const float* x      = (const float*)d_in[0];
  const float* w_attn = (const float*)d_in[1];
  const float* w_proj = (const float*)d_in[2];
  float* out = (float*)d_out;
  char* ws = (char*)d_ws;
  __hip_bfloat16* xb   = (__hip_bfloat16*)(ws);
  __hip_bfloat16* wat  = (__hip_bfloat16*)(ws + 8388608);
  __hip_bfloat16* wpt  = (__hip_bfloat16*)(ws + 14680064);
  __hip_bfloat16* qkvb = (__hip_bfloat16*)(ws + 16777216);
  __hip_bfloat16* yb   = (__hip_bfloat16*)(ws + 41943040);

  // 1) x -> bf16
  cast_bf16_kernel<<<4096, 256, 0, stream>>>(x, xb, 4194304);
  // 2) weights -> transposed bf16
  transpose_cast_kernel<<<dim3(96, 32), dim3(32, 8), 0, stream>>>(w_attn, wat, 1024, 3072);
  transpose_cast_kernel<<<dim3(32, 32), dim3(32, 8), 0, stream>>>(w_proj, wpt, 1024, 1024);
  // 3) qkv = x @ w_attn   (M=4096, N=3072, K=1024)
  gemm_bt_kernel<__hip_bfloat16><<<dim3(24, 32), 256, 0, stream>>>(xb, wat, qkvb, 4096, 3072, 1024);
  // 4) attention -> yb
  attn_kernel<<<dim3(32, 16, 2), 256, 0, stream>>>(qkvb, yb);
  // 5) out = yb @ w_proj  (M=4096, N=1024, K=1024), fp32 out
  gemm_bt_kernel<float><<<dim3(8, 32), 256, 0, stream>>>(yb, wpt, out, 4096, 1024, 1024);
}

// Round 2
// 231.779 us; speedup vs baseline: 1.3756x; 1.3756x over previous
//
#include <hip/hip_runtime.h>
#include <hip/hip_bf16.h>

// B=2, T=2048, C=1024, H=16, Dh=64
// ws layout (bytes), total 44,040,192:
//   xb   [4096x1024] bf16 @ 0          -- reused as vt [2][16][64][2048] after qkv GEMM
//   wat  [3072x1024] bf16 @ 8388608    -- reused as yb [4096x1024] bf16 after qkv GEMM
//   qkv  [4096x3072] bf16 @ 16777216
//   wpt  [1024x1024] bf16 @ 41943040

typedef __attribute__((ext_vector_type(8))) __bf16 bf16x8;
typedef __attribute__((ext_vector_type(4))) float  floatx4;
typedef __attribute__((ext_vector_type(4))) float  fvec4;
typedef __attribute__((ext_vector_type(4))) short  short4v;

#define MFMA16(a, b, c) __builtin_amdgcn_mfma_f32_16x16x32_bf16(a, b, c, 0, 0, 0)

__device__ inline void store_out(float* p, float v) { *p = v; }
__device__ inline void store_out(__hip_bfloat16* p, float v) { *p = __float2bfloat16(v); }

// ---------------- cast fp32 -> bf16 ----------------
__global__ __launch_bounds__(256) void cast_bf16_kernel(const float* __restrict__ in,
                                                        __hip_bfloat16* __restrict__ out,
                                                        int n) {
  int i = (blockIdx.x * 256 + threadIdx.x) * 4;
  if (i >= n) return;
  fvec4 v = *(const fvec4*)(in + i);
  union { short4v s; __hip_bfloat16 h[4]; } u;
#pragma unroll
  for (int j = 0; j < 4; ++j) u.h[j] = __float2bfloat16(v[j]);
  *(short4v*)((short*)out + i) = u.s;
}

// ------------- transpose + cast: in[rows][cols] f32 -> out[cols][rows] bf16 -------------
__global__ __launch_bounds__(256) void transpose_cast_kernel(const float* __restrict__ in,
                                                             __hip_bfloat16* __restrict__ out,
                                                             int rows, int cols) {
  __shared__ float tile[32][33];
  const int tx = threadIdx.x, ty = threadIdx.y;
  const int c0 = blockIdx.x * 32, r0 = blockIdx.y * 32;
#pragma unroll
  for (int i = 0; i < 32; i += 8)
    tile[ty + i][tx] = in[(long)(r0 + ty + i) * cols + c0 + tx];
  __syncthreads();
#pragma unroll
  for (int i = 0; i < 32; i += 8)
    out[(long)(c0 + ty + i) * rows + r0 + tx] = __float2bfloat16(tile[tx][ty + i]);
}

// ------------- V^T extraction: vt[b][h][d][t] = qkv[b*T+t][2048+h*64+d] -------------
// 64x64 tile via XOR-swizzled LDS (stride 64, phys colgrp = colgrp ^ ((row>>3)&7)):
// both the b128 writes and the column-gather reads are bank-conflict-free.
__global__ __launch_bounds__(256) void vt_kernel(const __hip_bfloat16* __restrict__ qkv,
                                                 __hip_bfloat16* __restrict__ vt) {
  __shared__ __align__(16) __hip_bfloat16 tile[64 * 64];
  const int tid = threadIdx.x;
  const int tt0 = blockIdx.x * 64, h = blockIdx.y, b = blockIdx.z;
  const long bh = (long)b * 16 + h;
#pragma unroll
  for (int it = 0; it < 2; ++it) {
    const int c = it * 256 + tid;
    const int row = c >> 3, cg = c & 7;
    const int pg = cg ^ ((row >> 3) & 7);
    *(bf16x8*)(tile + row * 64 + pg * 8) =
        *(const bf16x8*)(qkv + ((long)b * 2048 + tt0 + row) * 3072 + 2048 + h * 64 + cg * 8);
  }
  __syncthreads();
#pragma unroll
  for (int it = 0; it < 2; ++it) {
    const int c = it * 256 + tid;
    const int dr = c >> 3, tg = c & 7;
    union { bf16x8 v; __hip_bfloat16 e[8]; } u;
    const int pg = (dr >> 3) ^ tg;  // (row>>3)&7 == tg for row = tg*8+j
#pragma unroll
    for (int j = 0; j < 8; ++j)
      u.e[j] = tile[(tg * 8 + j) * 64 + pg * 8 + (dr & 7)];
    *(bf16x8*)(vt + (bh * 64 + dr) * 2048 + tt0 + tg * 8) = u.v;
  }
}

// ------------- GEMM: C[M,N] = A[M,K] * Bt[N,K]^T -------------
template <typename OutT>
__global__ __launch_bounds__(256) void gemm_bt_kernel(const __hip_bfloat16* __restrict__ A,
                                                      const __hip_bfloat16* __restrict__ Bt,
                                                      OutT* __restrict__ C,
                                                      int M, int N, int K) {
  __shared__ __align__(16) __hip_bfloat16 As[128 * 40];
  __shared__ __align__(16) __hip_bfloat16 Bs[128 * 40];
  const int tid = threadIdx.x;
  const int lane = tid & 63, wv = tid >> 6;
  const int l15 = lane & 15, quad = lane >> 4;
  const int wm = wv >> 1, wn = wv & 1;
  const long m0 = (long)blockIdx.y * 128, n0 = (long)blockIdx.x * 128;
  floatx4 acc[4][4] = {};
  const int nk = K >> 5;
  for (int kt = 0; kt < nk; ++kt) {
    const int k0 = kt << 5;
    __syncthreads();
#pragma unroll
    for (int it = 0; it < 2; ++it) {
      const int c = it * 256 + tid;
      const int row = c >> 2, col = (c & 3) << 3;
      *(bf16x8*)(As + row * 40 + col) = *(const bf16x8*)(A + (m0 + row) * K + k0 + col);
      *(bf16x8*)(Bs + row * 40 + col) = *(const bf16x8*)(Bt + (n0 + row) * K + k0 + col);
    }
    __syncthreads();
    bf16x8 af[4], bfr[4];
#pragma unroll
    for (int t = 0; t < 4; ++t) {
      af[t]  = *(const bf16x8*)(As + (wm * 64 + t * 16 + l15) * 40 + quad * 8);
      bfr[t] = *(const bf16x8*)(Bs + (wn * 64 + t * 16 + l15) * 40 + quad * 8);
    }
#pragma unroll
    for (int mt = 0; mt < 4; ++mt)
#pragma unroll
      for (int nt = 0; nt < 4; ++nt)
        acc[mt][nt] = MFMA16(af[mt], bfr[nt], acc[mt][nt]);
  }
#pragma unroll
  for (int mt = 0; mt < 4; ++mt)
#pragma unroll
    for (int nt = 0; nt < 4; ++nt)
#pragma unroll
      for (int r = 0; r < 4; ++r) {
        const long row = m0 + wm * 64 + mt * 16 + quad * 4 + r;
        const long col = n0 + wn * 64 + nt * 16 + l15;
        store_out(C + row * N + col, acc[mt][nt][r]);
      }
}

// ------------- paired-tile flash attention -------------
// block = (pair pt, head h, batch b): q-tiles qtA=pt, qtB=31-pt -> 33 active tiles/pair.
// 4 waves x 16 q-rows per tile. K-tile/Vt-tile staged once, frags shared by both tiles.
// Row-sum l via ones-row MFMA column (Vt row 64 == 1.0).
__global__ __launch_bounds__(256, 2) void attn_kernel(const __hip_bfloat16* __restrict__ qkv,
                                                      const __hip_bfloat16* __restrict__ vtg,
                                                      __hip_bfloat16* __restrict__ y) {
  __shared__ __align__(16) __hip_bfloat16 Ks[64 * 72];
  __shared__ __align__(16) __hip_bfloat16 Vt[80 * 72];
  __shared__ __align__(16) __hip_bfloat16 Ps[2 * 4 * 16 * 72];
  const int tid = threadIdx.x;
  const int lane = tid & 63, wv = tid >> 6;
  const int l15 = lane & 15, quad = lane >> 4;
  const int pt = blockIdx.x, h = blockIdx.y, b = blockIdx.z;
  const int qtA = pt, qtB = 31 - pt;
  const int q0A = qtA * 64, q0B = qtB * 64;
  const long bh = (long)b * 16 + h;
  const long RS = 3072;
  const float SC = 0.18033688011112042f;  // (1/8) * log2(e)

  // constant rows 64..79 of Vt: row 64 = ones (row-sum column), rest zeros
  for (int i = tid; i < 16 * 64; i += 256) {
    const int r = i >> 6, cc = i & 63;
    Vt[(64 + r) * 72 + cc] = __float2bfloat16(r == 0 ? 1.0f : 0.0f);
  }

  // Q A-fragments for both tiles (held in registers for the whole kernel)
  bf16x8 aqA0, aqA1, aqB0, aqB1;
  {
    const __hip_bfloat16* qpA = qkv + ((long)b * 2048 + q0A + wv * 16 + l15) * RS + h * 64 + quad * 8;
    aqA0 = *(const bf16x8*)qpA;
    aqA1 = *(const bf16x8*)(qpA + 32);
    const __hip_bfloat16* qpB = qkv + ((long)b * 2048 + q0B + wv * 16 + l15) * RS + h * 64 + quad * 8;
    aqB0 = *(const bf16x8*)qpB;
    aqB1 = *(const bf16x8*)(qpB + 32);
  }

  float mA[4], mB[4];
  floatx4 oA[4] = {}, oB[4] = {}, o4A = {}, o4B = {};
#pragma unroll
  for (int r = 0; r < 4; ++r) { mA[r] = -1e30f; mB[r] = -1e30f; }

  __hip_bfloat16* PsA = Ps + wv * 1152;
  __hip_bfloat16* PsB = Ps + 4608 + wv * 1152;

  for (int kt = 0; kt <= qtB; ++kt) {
    const int kb = kt * 64;
    const bool actA = (kt <= qtA);
    __syncthreads();  // protect Ks/Vt against previous iteration's frag readers
#pragma unroll
    for (int it = 0; it < 2; ++it) {
      const int c = it * 256 + tid;
      const int row = c >> 3, col = (c & 7) << 3;
      *(bf16x8*)(Ks + row * 72 + col) =
          *(const bf16x8*)(qkv + ((long)b * 2048 + kb + row) * RS + 1024 + h * 64 + col);
      *(bf16x8*)(Vt + row * 72 + col) =
          *(const bf16x8*)(vtg + (bh * 64 + row) * 2048 + kb + col);
    }
    __syncthreads();

    // K fragments, shared by both q-tiles
    bf16x8 kf[4][2];
#pragma unroll
    for (int nt = 0; nt < 4; ++nt) {
      const __hip_bfloat16* kp = Ks + (nt * 16 + l15) * 72 + quad * 8;
      kf[nt][0] = *(const bf16x8*)kp;
      kf[nt][1] = *(const bf16x8*)(kp + 32);
    }

    floatx4 sB4[4] = {}, sA4[4] = {};
#pragma unroll
    for (int nt = 0; nt < 4; ++nt) {
      sB4[nt] = MFMA16(aqB0, kf[nt][0], sB4[nt]);
      sB4[nt] = MFMA16(aqB1, kf[nt][1], sB4[nt]);
    }
    if (actA) {
#pragma unroll
      for (int nt = 0; nt < 4; ++nt) {
        sA4[nt] = MFMA16(aqA0, kf[nt][0], sA4[nt]);
        sA4[nt] = MFMA16(aqA1, kf[nt][1], sA4[nt]);
      }
    }

    auto do_softmax = [&](floatx4* s4, float* m, floatx4* o, floatx4& o4,
                          __hip_bfloat16* PsX, bool diag, int q0X) {
      float sv[4][4];
#pragma unroll
      for (int nt = 0; nt < 4; ++nt)
#pragma unroll
        for (int r = 0; r < 4; ++r) {
          float v = s4[nt][r] * SC;
          if (diag) {
            const int kg = kb + nt * 16 + l15;
            const int qg = q0X + wv * 16 + quad * 4 + r;
            if (kg > qg) v = -3.0e38f;
          }
          sv[nt][r] = v;
        }
#pragma unroll
      for (int r = 0; r < 4; ++r) {
        float mx = fmaxf(fmaxf(sv[0][r], sv[1][r]), fmaxf(sv[2][r], sv[3][r]));
#pragma unroll
        for (int off = 1; off < 16; off <<= 1) mx = fmaxf(mx, __shfl_xor(mx, off, 64));
        const float mn = fmaxf(m[r], mx);
        const float al = exp2f(m[r] - mn);
        m[r] = mn;
#pragma unroll
        for (int nt = 0; nt < 4; ++nt) {
          const float p = exp2f(sv[nt][r] - mn);
          PsX[(quad * 4 + r) * 72 + nt * 16 + l15] = __float2bfloat16(p);
          o[nt][r] *= al;
        }
        o4[r] *= al;
      }
    };

    do_softmax(sB4, mB, oB, o4B, PsB, kt == qtB, q0B);
    if (actA) do_softmax(sA4, mA, oA, o4A, PsA, kt == qtA, q0A);

    // V^T fragments (rows 0..79 incl. ones row), shared by both q-tiles
    bf16x8 vf[5][2];
#pragma unroll
    for (int nt = 0; nt < 5; ++nt) {
      const __hip_bfloat16* vp = Vt + (nt * 16 + l15) * 72 + quad * 8;
      vf[nt][0] = *(const bf16x8*)vp;
      vf[nt][1] = *(const bf16x8*)(vp + 32);
    }
    {
      const __hip_bfloat16* pp = PsB + l15 * 72 + quad * 8;
      const bf16x8 p0 = *(const bf16x8*)pp, p1 = *(const bf16x8*)(pp + 32);
#pragma unroll
      for (int nt = 0; nt < 4; ++nt) {
        oB[nt] = MFMA16(p0, vf[nt][0], oB[nt]);
        oB[nt] = MFMA16(p1, vf[nt][1], oB[nt]);
      }
      o4B = MFMA16(p0, vf[4][0], o4B);
      o4B = MFMA16(p1, vf[4][1], o4B);
    }
    if (actA) {
      const __hip_bfloat16* pp = PsA + l15 * 72 + quad * 8;
      const bf16x8 p0 = *(const bf16x8*)pp, p1 = *(const bf16x8*)(pp + 32);
#pragma unroll
      for (int nt = 0; nt < 4; ++nt) {
        oA[nt] = MFMA16(p0, vf[nt][0], oA[nt]);
        oA[nt] = MFMA16(p1, vf[nt][1], oA[nt]);
      }
      o4A = MFMA16(p0, vf[4][0], o4A);
      o4A = MFMA16(p1, vf[4][1], o4A);
    }
  }

  auto epilogue = [&](floatx4* o, floatx4& o4, int q0X) {
#pragma unroll
    for (int r = 0; r < 4; ++r) {
      const float lv = __shfl(o4[r], lane & 48, 64);  // lane quad*16 holds the row-sum
      const float inv = 1.0f / lv;
      const long t = (long)b * 2048 + q0X + wv * 16 + quad * 4 + r;
#pragma unroll
      for (int nt = 0; nt < 4; ++nt)
        y[t * 1024 + h * 64 + nt * 16 + l15] = __float2bfloat16(o[nt][r] * inv);
    }
  };
  epilogue(oA, o4A, q0A);
  epilogue(oB, o4B, q0B);
}

extern "C" void kernel_launch(void* const* d_in, const int* in_sizes, int n_in,
                              void* d_out, int out_size, void* d_ws, size_t ws_size,
                              hipStream_t stream) {
  const float* x      = (const float*)d_in[0];
  const float* w_attn = (const float*)d_in[1];
  const float* w_proj = (const float*)d_in[2];
  float* out = (float*)d_out;
  char* ws = (char*)d_ws;
  __hip_bfloat16* xb   = (__hip_bfloat16*)(ws);               // then vt
  __hip_bfloat16* wat  = (__hip_bfloat16*)(ws + 8388608);     // then yb
  __hip_bfloat16* qkvb = (__hip_bfloat16*)(ws + 16777216);
  __hip_bfloat16* wpt  = (__hip_bfloat16*)(ws + 41943040);
  __hip_bfloat16* vtg  = xb;
  __hip_bfloat16* yb   = wat;

  cast_bf16_kernel<<<4096, 256, 0, stream>>>(x, xb, 4194304);
  transpose_cast_kernel<<<dim3(96, 32), dim3(32, 8), 0, stream>>>(w_attn, wat, 1024, 3072);
  transpose_cast_kernel<<<dim3(32, 32), dim3(32, 8), 0, stream>>>(w_proj, wpt, 1024, 1024);
  // qkv = x @ w_attn
  gemm_bt_kernel<__hip_bfloat16><<<dim3(24, 32), 256, 0, stream>>>(xb, wat, qkvb, 4096, 3072, 1024);
  // V^T (overwrites xb -- xb is dead after the qkv GEMM)
  vt_kernel<<<dim3(32, 16, 2), 256, 0, stream>>>(qkvb, vtg);
  // attention (writes yb over wat -- wat is dead after the qkv GEMM)
  attn_kernel<<<dim3(16, 16, 2), 256, 0, stream>>>(qkvb, vtg, yb);
  // out = y @ w_proj
  gemm_bt_kernel<float><<<dim3(8, 32), 256, 0, stream>>>(yb, wpt, out, 4096, 1024, 1024);
}